// Round 1
// 286.271 us; speedup vs baseline: 1.0009x; 1.0009x over previous
//
#include <hip/hip_runtime.h>

typedef unsigned short u16;
typedef __attribute__((ext_vector_type(8))) short short8;
typedef __attribute__((ext_vector_type(4))) unsigned short u16x4;
typedef __attribute__((ext_vector_type(4))) float f32x4;

#define N_TOKENS 32768
#define EMBED 512
#define NCLS 16
#define NBATCH 8
#define NHEAD 8
#define DHEAD 64

__device__ __forceinline__ u16 f2bf(float f) {
  unsigned u = __float_as_uint(f);
  u += 0x7fffu + ((u >> 16) & 1u);   // RNE
  return (u16)(u >> 16);
}

__device__ __forceinline__ void async16(const u16* g, u16* l) {
  __builtin_amdgcn_global_load_lds(
      (__attribute__((address_space(1))) const unsigned int*)(const void*)g,
      (__attribute__((address_space(3))) unsigned int*)(void*)l,
      16, 0, 0);
}

// Raw barrier: does NOT drain vmcnt (unlike __syncthreads). Memory-clobber asm +
// sched_barrier pin ordering of LDS reads / DMA issues across it.
#define BARRIER()                                    \
  do {                                               \
    __builtin_amdgcn_sched_barrier(0);               \
    asm volatile("" ::: "memory");                   \
    __builtin_amdgcn_s_barrier();                    \
    asm volatile("" ::: "memory");                   \
    __builtin_amdgcn_sched_barrier(0);               \
  } while (0)

#define WAITV(N) asm volatile("s_waitcnt vmcnt(" #N ")" ::: "memory")
#define WAITLGKM() asm volatile("s_waitcnt lgkmcnt(0)" ::: "memory")

// ---------------- fp32 -> bf16 converter (4 elems/thread) ----------------
__global__ __launch_bounds__(256) void cvt_bf16(const float4* __restrict__ in,
                                                u16x4* __restrict__ out, int n4) {
  int i = blockIdx.x * blockDim.x + threadIdx.x;
  if (i >= n4) return;
  float4 v = in[i];
  u16x4 o;
  o[0] = f2bf(v.x); o[1] = f2bf(v.y); o[2] = f2bf(v.z); o[3] = f2bf(v.w);
  out[i] = o;
}

// ---------------- K/V projection ----------------
__global__ __launch_bounds__(256) void kvproj_kernel(
    const float* __restrict__ key, const float* __restrict__ val,
    const float* __restrict__ Wk, const float* __restrict__ bk,
    const float* __restrict__ Wv, const float* __restrict__ bv,
    float* __restrict__ kproj, float* __restrict__ vproj) {
  int t = blockIdx.x * blockDim.x + threadIdx.x;   // [0, 2*65536)
  const bool isV = t >= 65536;                      // wave-uniform
  int idx = t & 65535;
  int f = idx & 511;
  int bl = idx >> 9;
  int l = bl & 15;
  int b = bl >> 4;
  const float* src = isV ? val : key;
  const float* W = isV ? Wv : Wk;
  const float* bias = isV ? bv : bk;
  const float4* s4 = (const float4*)(src + (size_t)l * (NBATCH * EMBED) + (size_t)b * EMBED);
  const float4* w4 = (const float4*)(W + (size_t)f * EMBED);
  float acc = 0.f;
#pragma unroll 8
  for (int e = 0; e < EMBED / 4; e++) {
    float4 a = s4[e], w = w4[e];
    acc += a.x * w.x + a.y * w.y + a.z * w.z + a.w * w.w;
  }
  acc += bias[f];
  if (!isV) {
    kproj[((size_t)(b * EMBED + f)) * NCLS + l] = acc;           // [b][h][d][l]
  } else {
    int h = f >> 6, d = f & 63;
    vproj[(size_t)b * 8192 + (size_t)h * 1024 + l * 64 + d] = acc;  // [b][h][l][d]
  }
}

// ---------------- Kq[b][hl][e] = sum_d Wq[h*64+d][e] * kproj[b,h,d,l]  (bf16) ----
__global__ __launch_bounds__(256) void build_kq(const float* __restrict__ kproj,
                                                const float* __restrict__ Wq,
                                                u16* __restrict__ Kqb) {
  int t = blockIdx.x * 256 + threadIdx.x;   // 8*128*512
  int e = t & 511;
  int hl = (t >> 9) & 127;
  int b = t >> 16;
  int h = hl >> 4, l = hl & 15;
  const float* kp = kproj + (size_t)b * 8192 + h * 1024 + l;
  const float* wq = Wq + (size_t)(h * 64) * 512 + e;
  float acc = 0.f;
#pragma unroll 16
  for (int d = 0; d < 64; d++) acc += kp[d * 16] * wq[d * 512];
  Kqb[t] = f2bf(acc);
}

// ---------------- sb[b][hl] = sum_d bq[h*64+d] * kproj[b,h,d,l] ----------------
__global__ void build_sb(const float* __restrict__ kproj, const float* __restrict__ bq,
                         float* __restrict__ sb) {
  int t = blockIdx.x * 256 + threadIdx.x;   // 1024
  int hl = t & 127, b = t >> 7;
  int h = hl >> 4, l = hl & 15;
  const float* kp = kproj + (size_t)b * 8192 + h * 1024 + l;
  const float* q = bq + h * 64;
  float acc = 0.f;
#pragma unroll
  for (int d = 0; d < 64; d++) acc += q[d] * kp[d * 16];
  sb[t] = acc;
}

// ---------------- WoV[b][f][hl] = sum_d vproj[b,h,l,d] * Wo[f][h*64+d]  (bf16) ----
__global__ __launch_bounds__(256) void build_wov(const float* __restrict__ vproj,
                                                 const float* __restrict__ Wo,
                                                 u16* __restrict__ WoVb) {
  int t = blockIdx.x * 256 + threadIdx.x;   // 8*512*128
  int hl = t & 127;
  int f = (t >> 7) & 511;
  int b = t >> 16;
  int h = hl >> 4, l = hl & 15;
  const float* vp = vproj + (size_t)b * 8192 + h * 1024 + l * 64;
  const float* wo = Wo + (size_t)f * 512 + h * 64;
  float acc = 0.f;
#pragma unroll 16
  for (int d = 0; d < 64; d++) acc += vp[d] * wo[d];
  WoVb[t] = f2bf(acc);
}

// ---------------- fused: scores GEMM + softmax + out GEMM ----------------
// Per block: 128 tokens. Phase 1: C[128,128] = qbf[128,512] x Kq[bb]^T with
// depth-4 circular LDS staging and counted vmcnt (never drain in-loop).
// Softmax per head's 16 l-cols via 16-lane shfl reductions -> P bf16 in LDS
// (XOR-swizzled). Phase 2: out[128,512] = P x WoV[bb]^T, B staged in 128-col
// chunks double-buffered across the As/Bs regions. Predicated store per row's
// batch (bidx sorted -> bb in [bFirst,bLast]).
// All LDS tiles XOR-swizzled at 16B-chunk granularity; global_load_lds keeps a
// LINEAR LDS dest and the swizzle is pre-applied to the global source address.
__global__ __launch_bounds__(256) void fused_attn(
    const u16* __restrict__ A, const u16* __restrict__ Kqb,
    const u16* __restrict__ WoVb, const float* __restrict__ sb,
    const float* __restrict__ bo, const int* __restrict__ bidx,
    float* __restrict__ out) {
  __shared__ __align__(16) u16 As[4][4096];   // 32 KB: score A slots / out-B buf0
  __shared__ __align__(16) u16 Bs[4][4096];   // 32 KB: score B slots / out-B buf1
  __shared__ __align__(16) u16 Ps[16384];     // 32 KB: P [128][128] swizzled
  const int tid = threadIdx.x;
  const int lane = tid & 63;
  const int wave = tid >> 6;
  const int wr = (wave >> 1) * 64;
  const int wc = (wave & 1) * 64;
  const int quad = lane >> 4;
  const int l16 = lane & 15;
  const int m0 = blockIdx.x * 128;
  const int bFirst = bidx[m0];
  const int bLast = bidx[m0 + 127];

  // score-phase staging coords: 512 chunks of 16B per 8KB tile; this thread owns
  // chunks c0=tid, c1=tid+256. Source address carries the inverse swizzle.
  const int r0 = tid >> 2;
  const int r1 = r0 + 64;
  const int lg0 = (tid & 3) ^ ((r0 >> 1) & 3);
  const int lg1 = (tid & 3) ^ ((r1 >> 1) & 3);
  const size_t aoff0 = (size_t)(m0 + r0) * 512 + lg0 * 8;
  const size_t aoff1 = (size_t)(m0 + r1) * 512 + lg1 * 8;
  const size_t boff0 = (size_t)r0 * 512 + lg0 * 8;
  const size_t boff1 = (size_t)r1 * 512 + lg1 * 8;

#define STAGE_AB(T, S)                                   \
  do {                                                   \
    async16(A + aoff0 + (T) * 32, &As[S][tid * 8]);      \
    async16(A + aoff1 + (T) * 32, &As[S][tid * 8 + 2048]); \
    async16(Bq + boff0 + (T) * 32, &Bs[S][tid * 8]);     \
    async16(Bq + boff1 + (T) * 32, &Bs[S][tid * 8 + 2048]); \
  } while (0)

#define STAGE_W(C, DST)                                                        \
  do {                                                                         \
    _Pragma("unroll")                                                          \
    for (int h = 0; h < 8; h++) {                                              \
      int p = tid + h * 256;                                                   \
      int fr = p >> 4;                                                         \
      int lg = (p & 15) ^ (fr & 7);                                            \
      async16(WoVb + (size_t)bb * 65536 + (size_t)((C) * 128 + fr) * 128 + lg * 8, \
              (DST) + p * 8);                                                  \
    }                                                                          \
  } while (0)

  int rowb[4][4];
#pragma unroll
  for (int mi = 0; mi < 4; mi++)
#pragma unroll
    for (int r = 0; r < 4; r++) rowb[mi][r] = bidx[m0 + wr + mi * 16 + quad * 4 + r];

  for (int bb = bFirst; bb <= bLast; bb++) {
    const u16* Bq = Kqb + (size_t)bb * 65536;

    BARRIER();                 // protect staging regions vs previous bb's readers
    STAGE_AB(0, 0);
    STAGE_AB(1, 1);
    STAGE_AB(2, 2);            // 12 loads in flight

    f32x4 acc[4][4];
#pragma unroll
    for (int i = 0; i < 4; i++)
#pragma unroll
      for (int j = 0; j < 4; j++) acc[i][j] = (f32x4){0.f, 0.f, 0.f, 0.f};

#pragma unroll
    for (int t = 0; t < 16; t++) {
      // entry in-flight = 4*min(3,16-t); tile t done at:
      if (t <= 13) { WAITV(8); } else if (t == 14) { WAITV(4); } else { WAITV(0); }
      BARRIER();
      if (t <= 12) STAGE_AB(t + 3, (t + 3) & 3);   // refill; stays in flight across barriers
      const u16* as = As[t & 3];
      const u16* bs = Bs[t & 3];
      short8 af[4], bfr[4];
#pragma unroll
      for (int mi = 0; mi < 4; mi++) {
        const int row = wr + mi * 16 + l16;
        af[mi] = *(const short8*)&as[row * 32 + ((quad ^ ((row >> 1) & 3)) << 3)];
      }
#pragma unroll
      for (int ni = 0; ni < 4; ni++) {
        const int rw = wc + ni * 16 + l16;
        bfr[ni] = *(const short8*)&bs[rw * 32 + ((quad ^ ((rw >> 1) & 3)) << 3)];
      }
#pragma unroll
      for (int mi = 0; mi < 4; mi++)
#pragma unroll
        for (int ni = 0; ni < 4; ni++)
          acc[mi][ni] = __builtin_amdgcn_mfma_f32_16x16x32_bf16(af[mi], bfr[ni], acc[mi][ni], 0, 0, 0);
    }

    // ---- softmax over each head's 16 l-cols; P -> LDS (swizzled), all rows ----
    float sbv[4];
#pragma unroll
    for (int ni = 0; ni < 4; ni++) sbv[ni] = sb[bb * 128 + wc + ni * 16 + l16];
#pragma unroll
    for (int mi = 0; mi < 4; mi++) {
#pragma unroll
      for (int r = 0; r < 4; r++) {
        const int row = wr + mi * 16 + quad * 4 + r;   // local row
#pragma unroll
        for (int ni = 0; ni < 4; ni++) {
          float v = acc[mi][ni][r] + sbv[ni];
          float mx = v;
          mx = fmaxf(mx, __shfl_xor(mx, 1));
          mx = fmaxf(mx, __shfl_xor(mx, 2));
          mx = fmaxf(mx, __shfl_xor(mx, 4));
          mx = fmaxf(mx, __shfl_xor(mx, 8));
          float ev = __expf((v - mx) * 0.125f);   // scale = D^-0.5
          float s = ev;
          s += __shfl_xor(s, 1);
          s += __shfl_xor(s, 2);
          s += __shfl_xor(s, 4);
          s += __shfl_xor(s, 8);
          const int col = wc + ni * 16 + l16;
          Ps[row * 128 + (((col >> 3) ^ (row & 7)) << 3) + (col & 7)] = f2bf(ev / s);
        }
      }
    }
    WAITLGKM();                // P writes visible before anyone reads
    BARRIER();

    // ---- phase 2: out = P x WoV[bb]^T, 4 chunks of 128 f-cols ----
    short8 pa[4][4];           // hoist P fragments: [kk][mi], read Ps once
#pragma unroll
    for (int kk = 0; kk < 4; kk++)
#pragma unroll
      for (int mi = 0; mi < 4; mi++) {
        const int row = wr + mi * 16 + l16;
        pa[kk][mi] = *(const short8*)&Ps[row * 128 + (((kk * 4 + quad) ^ (row & 7)) << 3)];
      }
    STAGE_W(0, &As[0][0]);     // chunk 0 -> buf0 (As region)

#pragma unroll
    for (int c = 0; c < 4; c++) {
      WAITV(0);                // chunk c staged (issued one chunk early)
      BARRIER();
      if (c < 3) {
        u16* dstW = ((c + 1) & 1) ? &Bs[0][0] : &As[0][0];
        STAGE_W(c + 1, dstW);  // overlaps with compute below
      }
      const u16* bs2 = (c & 1) ? &Bs[0][0] : &As[0][0];
      f32x4 acc2[4][4];
#pragma unroll
      for (int i = 0; i < 4; i++)
#pragma unroll
        for (int j = 0; j < 4; j++) acc2[i][j] = (f32x4){0.f, 0.f, 0.f, 0.f};
#pragma unroll
      for (int kk = 0; kk < 4; kk++) {
        short8 bf2[4];
#pragma unroll
        for (int ni = 0; ni < 4; ni++) {
          const int fr = wc + ni * 16 + l16;
          bf2[ni] = *(const short8*)&bs2[fr * 128 + (((kk * 4 + quad) ^ (fr & 7)) << 3)];
        }
#pragma unroll
        for (int mi = 0; mi < 4; mi++)
#pragma unroll
          for (int ni = 0; ni < 4; ni++)
            acc2[mi][ni] = __builtin_amdgcn_mfma_f32_16x16x32_bf16(pa[kk][mi], bf2[ni], acc2[mi][ni], 0, 0, 0);
      }
      float bov[4];
#pragma unroll
      for (int ni = 0; ni < 4; ni++) bov[ni] = bo[c * 128 + wc + ni * 16 + l16];
#pragma unroll
      for (int mi = 0; mi < 4; mi++)
#pragma unroll
        for (int r = 0; r < 4; r++) {
          if (rowb[mi][r] == bb) {
            const size_t row = m0 + wr + mi * 16 + quad * 4 + r;
#pragma unroll
            for (int ni = 0; ni < 4; ni++)
              out[row * 512 + c * 128 + wc + ni * 16 + l16] = acc2[mi][ni][r] + bov[ni];
          }
        }
    }
  }
#undef STAGE_AB
#undef STAGE_W
}

extern "C" void kernel_launch(void* const* d_in, const int* in_sizes, int n_in,
                              void* d_out, int out_size, void* d_ws, size_t ws_size,
                              hipStream_t stream) {
  const float* query = (const float*)d_in[0];
  const float* keyt = (const float*)d_in[1];
  const float* valt = (const float*)d_in[2];
  const int* bidx = (const int*)d_in[3];
  // d_in[4] = batch_size (scalar, fixed = 8)
  const float* Wq = (const float*)d_in[5];
  const float* bq = (const float*)d_in[6];
  const float* Wk = (const float*)d_in[7];
  const float* bk = (const float*)d_in[8];
  const float* Wv = (const float*)d_in[9];
  const float* bv = (const float*)d_in[10];
  const float* Wo = (const float*)d_in[11];
  const float* bo = (const float*)d_in[12];
  float* out = (float*)d_out;

  // workspace layout (bytes)
  unsigned char* w = (unsigned char*)d_ws;
  u16* qbf = (u16*)(w);                       // 33,554,432: query bf16 [N,E]
  float* kproj = (float*)(w + 41943040ull);   //    262,144: [B,H,D,L]
  float* vproj = (float*)(w + 42205184ull);   //    262,144: [B,H,L,D]
  u16* Kqb = (u16*)(w + 42467328ull);         //  1,048,576: [B,128,512] bf16
  u16* WoVb = (u16*)(w + 43515904ull);        //  1,048,576: [B,512,128] bf16
  float* sb = (float*)(w + 44564480ull);      //      4,096: [B,128]

  // 1) query -> bf16
  cvt_bf16<<<N_TOKENS * EMBED / 4 / 256, 256, 0, stream>>>(
      (const float4*)query, (u16x4*)qbf, N_TOKENS * EMBED / 4);

  // 2) K/V projections (fp32, tiny)
  kvproj_kernel<<<512, 256, 0, stream>>>(keyt, valt, Wk, bk, Wv, bv, kproj, vproj);

  // 3) fold Wq through k, Wo through v
  build_kq<<<2048, 256, 0, stream>>>(kproj, Wq, Kqb);
  build_sb<<<4, 256, 0, stream>>>(kproj, bq, sb);
  build_wov<<<2048, 256, 0, stream>>>(vproj, Wo, WoVb);

  // 4) fused scores + softmax + out
  fused_attn<<<N_TOKENS / 128, 256, 0, stream>>>(qbf, Kqb, WoVb, sb, bo, bidx, out);
}